// Round 1
// baseline (763.583 us; speedup 1.0000x reference)
//
#include <hip/hip_runtime.h>

// GCN 2-layer: N=100000 nodes, E=3200000 edges, 13 -> 32 -> 16 channels.
// Atomic-scatter aggregation; self-loops folded into accumulator init.

constexpr int N_NODES = 100000;
constexpr int N_EDGES = 3200000;
constexpr int IN_CH  = 13;
constexpr int HID_CH = 32;
constexpr int LAT_CH = 16;

// deg starts at 1.0 (self-loop)
__global__ __launch_bounds__(256) void k_deg_init(float* __restrict__ deg) {
    int i = blockIdx.x * 256 + threadIdx.x;
    if (i < N_NODES) deg[i] = 1.0f;
}

__global__ __launch_bounds__(256) void k_deg_accum(const int* __restrict__ dst,
                                                   float* __restrict__ deg) {
    int e = blockIdx.x * 256 + threadIdx.x;
    if (e < N_EDGES) atomicAdd(&deg[dst[e]], 1.0f);
}

__global__ __launch_bounds__(256) void k_dis(float* __restrict__ deg) {
    int i = blockIdx.x * 256 + threadIdx.x;
    if (i < N_NODES) deg[i] = 1.0f / sqrtf(deg[i]);  // deg >= 1 always (self-loop)
}

// xw = x @ W1 ; h_init = xw*dis^2 + b1  (self-loop term + bias)
// block = 256 threads = 8 nodes x 32 channels
__global__ __launch_bounds__(256) void k_xw1(const float* __restrict__ x,
                                             const float* __restrict__ W1,
                                             const float* __restrict__ b1,
                                             const float* __restrict__ dis,
                                             float* __restrict__ xw,
                                             float* __restrict__ h) {
    __shared__ float sW[IN_CH * HID_CH];
    for (int j = threadIdx.x; j < IN_CH * HID_CH; j += 256) sW[j] = W1[j];
    __syncthreads();
    int ch   = threadIdx.x & 31;
    int node = blockIdx.x * 8 + (threadIdx.x >> 5);
    if (node >= N_NODES) return;
    float sum = 0.f;
#pragma unroll
    for (int k = 0; k < IN_CH; ++k)
        sum += x[node * IN_CH + k] * sW[k * HID_CH + ch];
    float di = dis[node];
    xw[node * HID_CH + ch] = sum;
    h[node * HID_CH + ch]  = sum * di * di + b1[ch];
}

// h[dst] += xw[src] * dis[src]*dis[dst]  — one thread per (edge, channel)
__global__ __launch_bounds__(256) void k_scatter1(const int* __restrict__ src,
                                                  const int* __restrict__ dst,
                                                  const float* __restrict__ dis,
                                                  const float* __restrict__ xw,
                                                  float* __restrict__ h) {
    int idx = blockIdx.x * 256 + threadIdx.x;   // < 102.4M, fits int32
    int e  = idx >> 5;
    int ch = idx & 31;
    if (e >= N_EDGES) return;
    int s = src[e], d = dst[e];
    float w = dis[s] * dis[d];
    atomicAdd(&h[d * HID_CH + ch], xw[s * HID_CH + ch] * w);
}

// hw = relu(h) @ W2 ; out_init = hw*dis^2 + b2
// block = 256 threads = 16 nodes x 16 channels
__global__ __launch_bounds__(256) void k_xw2(const float* __restrict__ h,
                                             const float* __restrict__ W2,
                                             const float* __restrict__ b2,
                                             const float* __restrict__ dis,
                                             float* __restrict__ hw,
                                             float* __restrict__ out) {
    __shared__ float sW[HID_CH * LAT_CH];
    for (int j = threadIdx.x; j < HID_CH * LAT_CH; j += 256) sW[j] = W2[j];
    __syncthreads();
    int ch   = threadIdx.x & 15;
    int node = blockIdx.x * 16 + (threadIdx.x >> 4);
    if (node >= N_NODES) return;
    float sum = 0.f;
#pragma unroll
    for (int k = 0; k < HID_CH; ++k) {
        float hv = h[node * HID_CH + k];
        hv = hv > 0.f ? hv : 0.f;               // fused ReLU
        sum += hv * sW[k * LAT_CH + ch];
    }
    float di = dis[node];
    hw[node * LAT_CH + ch]  = sum;
    out[node * LAT_CH + ch] = sum * di * di + b2[ch];
}

__global__ __launch_bounds__(256) void k_scatter2(const int* __restrict__ src,
                                                  const int* __restrict__ dst,
                                                  const float* __restrict__ dis,
                                                  const float* __restrict__ hw,
                                                  float* __restrict__ out) {
    int idx = blockIdx.x * 256 + threadIdx.x;   // < 51.2M
    int e  = idx >> 4;
    int ch = idx & 15;
    if (e >= N_EDGES) return;
    int s = src[e], d = dst[e];
    float w = dis[s] * dis[d];
    atomicAdd(&out[d * LAT_CH + ch], hw[s * LAT_CH + ch] * w);
}

extern "C" void kernel_launch(void* const* d_in, const int* in_sizes, int n_in,
                              void* d_out, int out_size, void* d_ws, size_t ws_size,
                              hipStream_t stream) {
    const float* x  = (const float*)d_in[0];
    const int*   ei = (const int*)d_in[1];   // int64 in ref, but JAX x64 off -> int32
    const float* W1 = (const float*)d_in[2];
    const float* b1 = (const float*)d_in[3];
    const float* W2 = (const float*)d_in[4];
    const float* b2 = (const float*)d_in[5];
    float* out = (float*)d_out;

    const int* src = ei;            // edge_index[0]
    const int* dst = ei + N_EDGES;  // edge_index[1]

    // workspace layout (all 16B-aligned): dis[N] | xw[N*32] | h[N*32] | hw[N*16]
    char* ws = (char*)d_ws;
    float* dis = (float*)(ws);
    float* xw  = (float*)(ws + 400000);
    float* h   = (float*)(ws + 400000 + 12800000);
    float* hw  = (float*)(ws + 400000 + 2 * 12800000);
    // total: 32.4 MB

    k_deg_init <<<(N_NODES + 255) / 256, 256, 0, stream>>>(dis);
    k_deg_accum<<<(N_EDGES + 255) / 256, 256, 0, stream>>>(dst, dis);
    k_dis      <<<(N_NODES + 255) / 256, 256, 0, stream>>>(dis);
    k_xw1      <<<(N_NODES + 7) / 8,     256, 0, stream>>>(x, W1, b1, dis, xw, h);
    k_scatter1 <<<(N_EDGES * 32 + 255) / 256, 256, 0, stream>>>(src, dst, dis, xw, h);
    k_xw2      <<<(N_NODES + 15) / 16,   256, 0, stream>>>(h, W2, b2, dis, hw, out);
    k_scatter2 <<<(N_EDGES * 16 + 255) / 256, 256, 0, stream>>>(src, dst, dis, hw, out);
}